// Round 17
// baseline (463.461 us; speedup 1.0000x reference)
//
#include <hip/hip_runtime.h>
#include <cstdint>

#define N_NODES 100000
#define N_EDGES 500000
#define N_GRAPHS 128
#define HID 128
#define SCANH_B ((N_NODES + 255) / 256)       // 391 blocks per-layer scan
#define E256_G ((N_EDGES + 255) / 256)        // 1954 hist blocks (256 thr)
#define MM_G ((N_NODES + 127) / 128)          // 782 mm blocks
#define AH_G ((N_NODES + 511) / 512)          // 196 expand/zbound blocks (512 thr)
#define BH_G ((N_EDGES + 511) / 512)          // 977 scatter / hist2 blocks (512 thr)

typedef __attribute__((ext_vector_type(8))) short short8;
typedef __attribute__((ext_vector_type(4))) float f32x4;

// ---- monotone float<->uint encoding for max; enc==0 marks "never written" ----
__device__ __forceinline__ unsigned encf(float f) {
    unsigned u = __float_as_uint(f);
    return (u & 0x80000000u) ? ~u : (u | 0x80000000u);
}
__device__ __forceinline__ float decf(unsigned e) {
    unsigned u = (e & 0x80000000u) ? (e & 0x7FFFFFFFu) : ~e;
    return __uint_as_float(u);
}
// ---- hardware packed f32->bf16 (RNE, src0->low half). absmax 0.0078125 vs
//      manual round (1 bf16 ULP), accepted since R14; numerics frozen. ----
__device__ __forceinline__ unsigned cvt_pk_bf16(float lo, float hi) {
    unsigned r;
    asm("v_cvt_pk_bf16_f32 %0, %1, %2" : "=v"(r) : "v"(lo), "v"(hi));
    return r;
}
__device__ __forceinline__ ushort bf16r(float f) {
    unsigned u = __float_as_uint(f);
    return (ushort)((u + 0x7fffu + ((u >> 16) & 1u)) >> 16);
}
__device__ __forceinline__ float bf2f(ushort h) {
    return __uint_as_float((unsigned)h << 16);
}

// ---- D1: HIST LAYER 1 + transpose weights + prep + zero pooled. ----
__global__ __launch_bounds__(256) void prep_hist_kernel(const float* __restrict__ W1b,
                                                        const float* __restrict__ W2b,
                                                        const float* __restrict__ W1a,
                                                        const float* __restrict__ W2a,
                                                        const float* __restrict__ W_enc,
                                                        const float* __restrict__ b_enc,
                                                        const float* __restrict__ W0,
                                                        const float* __restrict__ b0,
                                                        ushort* __restrict__ WT,
                                                        float* __restrict__ wkey,
                                                        float* __restrict__ bias0,
                                                        float* __restrict__ pooled,
                                                        const int* __restrict__ dst1,
                                                        int* __restrict__ cnt,
                                                        int* __restrict__ seq) {
    int blk = blockIdx.x;
    int tid = threadIdx.x;
    if (blk < E256_G) {   // hist layer 1
        int e = blk * 256 + tid;
        if (e < N_EDGES) seq[e] = atomicAdd(&cnt[dst1[e]], 1);
        return;
    }
    int b2 = blk - E256_G;
    if (b2 < 384) {   // weight transpose
        int m = b2 >> 6;
        int i = (b2 & 63) * 256 + tid;   // i = n*128 + k
        int n = i >> 7, k = i & 127;
        int src = k * HID + n;
        float v;
        switch (m) {
            case 0: v = W1b[src]; break;
            case 1: v = W2b[src]; break;
            case 2: v = W1a[src]; break;
            case 3: v = W1a[HID * HID + src] - W1a[src]; break;
            case 4: v = W2a[src]; break;
            default: v = W2a[HID * HID + src] - W2a[src]; break;
        }
        WT[m * HID * HID + i] = bf16r(v);
        return;
    }
    if (b2 == 384) {   // prep
        if (tid < HID) {
            float wk = 0.f, bk = b0[tid];
            for (int k = 0; k < 32; ++k) {
                float w = W0[(15 + k) * HID + tid];
                wk += W_enc[k] * w;
                bk += b_enc[k] * w;
            }
            wkey[tid] = wk;
            bias0[tid] = bk;
        }
        return;
    }
    // zero pooled (exactly 256*256 = 65536 floats)
    pooled[(b2 - 385) * 256 + tid] = 0.f;
}

// ---- per-layer scan (N_NODES items): local-exclusive cursor + partials ----
__global__ __launch_bounds__(256) void scan_half_kernel(const int* __restrict__ cnt,
                                                        int* __restrict__ cursor,
                                                        int* __restrict__ partials) {
    __shared__ int tmp[256];
    int tid = threadIdx.x;
    int gid = blockIdx.x * 256 + tid;
    int v = (gid < N_NODES) ? cnt[gid] : 0;
    tmp[tid] = v;
    __syncthreads();
#pragma unroll
    for (int off = 1; off < 256; off <<= 1) {
        int t = (tid >= off) ? tmp[tid - off] : 0;
        __syncthreads();
        tmp[tid] += t;
        __syncthreads();
    }
    if (gid < N_NODES) cursor[gid] = tmp[tid] - v;   // local exclusive
    if (tid == 255) partials[blockIdx.x] = tmp[255];
}

__global__ __launch_bounds__(512) void scan2_half_kernel(int* __restrict__ partials) {
    __shared__ int tmp[512];
    int tid = threadIdx.x;
    int v = (tid < SCANH_B) ? partials[tid] : 0;
    tmp[tid] = v;
    __syncthreads();
#pragma unroll
    for (int off = 1; off < 512; off <<= 1) {
        int t = (tid >= off) ? tmp[tid - off] : 0;
        __syncthreads();
        tmp[tid] += t;
        __syncthreads();
    }
    if (tid < SCANH_B) partials[tid] = tmp[tid] - v;  // exclusive
}

// ---- D4 fused: roles INTERLEAVED by blockIdx%3 so every CU's resident set
//      mixes latency blocks (hist2/scatter1, atomic/scatter-stalled) with
//      compute blocks (mm1+encode/expand1). R16 proved consecutive-range
//      role layout cannot overlap: the first role (977 blocks) exceeds the
//      512-slot resident set, so CUs drain it serially. grid = 3*978. ----
__global__ __launch_bounds__(512, 4) void build_mm_kernel(const float* __restrict__ x,
                                                          const float* __restrict__ W0,
                                                          const float* __restrict__ wkey,
                                                          const float* __restrict__ bias0,
                                                          ushort* __restrict__ h,
                                                          float* __restrict__ xkey,
                                                          const ushort* __restrict__ WuT,
                                                          const ushort* __restrict__ WvT,
                                                          const float* __restrict__ bv,
                                                          ushort* __restrict__ outu,
                                                          ushort* __restrict__ outv,
                                                          const int* __restrict__ src1,
                                                          const int* __restrict__ dst1,
                                                          const int* __restrict__ dst2,
                                                          const int* __restrict__ cnt,
                                                          const int* __restrict__ cursor,
                                                          const int* __restrict__ partials1,
                                                          int* __restrict__ cnt2w,
                                                          int* __restrict__ seq,
                                                          int* __restrict__ srcS,
                                                          int* __restrict__ dstS,
                                                          unsigned* __restrict__ agg1) {
    __shared__ ushort sH[128 * 136];    // A-tile, then reused for D-restage
    __shared__ ushort sWT[128 * 136];   // Wu, then Wv
    int blk = blockIdx.x;
    int tid = threadIdx.x;

    int r3 = blk % 3, q3 = blk / 3;
    if (r3 < 2) {   // latency pool: hist2 then scatter1
        int li = q3 * 2 + r3;
        if (li < BH_G) {   // hist layer 2
            int e = li * 512 + tid;
            if (e < N_EDGES) seq[N_EDGES + e] = atomicAdd(&cnt2w[dst2[e]], 1);
            return;
        }
        li -= BH_G;
        if (li < BH_G) {   // scatter src (layer 1, atomic-free)
            int e = li * 512 + tid;
            if (e >= N_EDGES) return;
            int idx = dst1[e];
            int pos = cursor[idx] + partials1[idx >> 8] + seq[e];
            srcS[pos] = src1[e];
        }
        return;
    }
    int ci = q3;   // compute pool: mm1 then expand1
    if (ci >= MM_G) {
        int gid = (ci - MM_G) * 512 + tid;
        if (gid >= N_NODES) return;
        int c = cnt[gid];
        if (c == 0) return;
        int o = cursor[gid] + partials1[gid >> 8];
        for (int i = 0; i < c; ++i) dstS[o + i] = gid;
        bool spans = (o >> 4) != ((o + c - 1) >> 4);
        bool tail = (o + c == N_EDGES);
        if (spans || tail) {
            uint4* ap = (uint4*)(agg1 + (size_t)gid * HID);
#pragma unroll
            for (int i = 0; i < 32; ++i) ap[i] = make_uint4(0u, 0u, 0u, 0u);
        }
        return;
    }

    // ---- mm1 with inline encode ----
    int n0 = ci * 128;
#pragma unroll
    for (int q = 0; q < 4; ++q) {
        int c = q * 512 + tid;
        int r = c >> 4, off = (c & 15) << 3;
        int n = n0 + r;
        uint4 vv = make_uint4(0, 0, 0, 0);
        if (n < N_NODES) {
            const float* xr = x + n * 16;
            float k0 = xr[0];
            if (off == 0) xkey[n] = k0;
            float xf[15];
#pragma unroll
            for (int f = 0; f < 15; ++f) xf[f] = xr[1 + f];
            unsigned ow[4];
#pragma unroll
            for (int p = 0; p < 4; ++p) {
                int c0 = off + 2 * p;
                float a0 = bias0[c0] + k0 * wkey[c0];
                float a1 = bias0[c0 + 1] + k0 * wkey[c0 + 1];
#pragma unroll
                for (int f = 0; f < 15; ++f) {
                    float2 w2 = *(const float2*)(W0 + f * HID + c0);
                    a0 = fmaf(xf[f], w2.x, a0);
                    a1 = fmaf(xf[f], w2.y, a1);
                }
                ow[p] = cvt_pk_bf16(fmaxf(a0, 0.f), fmaxf(a1, 0.f));
            }
            vv = make_uint4(ow[0], ow[1], ow[2], ow[3]);
            *(uint4*)(h + (size_t)n * HID + off) = vv;
        }
        *(uint4*)(sH + r * 136 + off) = vv;
    }
    // stage Wu
#pragma unroll
    for (int q = 0; q < 4; ++q) {
        int c = q * 512 + tid;
        int nn = c >> 4, off = (c & 15) << 3;
        *(uint4*)(sWT + nn * 136 + off) = *(const uint4*)(WuT + nn * 128 + off);
    }
    __syncthreads();

    int lane = tid & 63, wv = tid >> 6;
    int l15 = lane & 15, quad = lane >> 4;
    int ch = wv & 1, rh = wv >> 1;

    short8 afr[2][4];
#pragma unroll
    for (int rr = 0; rr < 2; ++rr) {
        const ushort* ab = sH + (rh * 32 + rr * 16 + l15) * 136 + quad * 8;
#pragma unroll
        for (int kc = 0; kc < 4; ++kc)
            afr[rr][kc] = *(const short8*)(ab + kc * 32);
    }

#pragma unroll
    for (int pass = 0; pass < 2; ++pass) {
        ushort* out = pass ? outv : outu;
        f32x4 acc[2][4];
#pragma unroll
        for (int rr = 0; rr < 2; ++rr)
#pragma unroll
            for (int ct = 0; ct < 4; ++ct) acc[rr][ct] = (f32x4){0.f, 0.f, 0.f, 0.f};
#pragma unroll
        for (int kc = 0; kc < 4; ++kc) {
#pragma unroll
            for (int ct = 0; ct < 4; ++ct) {
                short8 bfr = *(const short8*)(sWT + ((ch * 4 + ct) * 16 + l15) * 136 + quad * 8 + kc * 32);
                acc[0][ct] = __builtin_amdgcn_mfma_f32_16x16x32_bf16(afr[0][kc], bfr, acc[0][ct], 0, 0, 0);
                acc[1][ct] = __builtin_amdgcn_mfma_f32_16x16x32_bf16(afr[1][kc], bfr, acc[1][ct], 0, 0, 0);
            }
        }
        __syncthreads();   // sWT + sH(afr) reads done
#pragma unroll
        for (int ct = 0; ct < 4; ++ct) {
            int col = (ch * 4 + ct) * 16 + l15;
            float bb = pass ? bv[col] : 0.f;
#pragma unroll
            for (int rr = 0; rr < 2; ++rr) {
                int rowb = rh * 32 + rr * 16 + quad * 4;
                unsigned p01 = cvt_pk_bf16(acc[rr][ct][0] + bb, acc[rr][ct][1] + bb);
                unsigned p23 = cvt_pk_bf16(acc[rr][ct][2] + bb, acc[rr][ct][3] + bb);
                sH[(rowb + 0) * 136 + col] = (ushort)p01;
                sH[(rowb + 1) * 136 + col] = (ushort)(p01 >> 16);
                sH[(rowb + 2) * 136 + col] = (ushort)p23;
                sH[(rowb + 3) * 136 + col] = (ushort)(p23 >> 16);
            }
        }
        if (pass == 0) {   // restage Wv over sWT (reads drained by the barrier above)
#pragma unroll
            for (int q = 0; q < 4; ++q) {
                int c = q * 512 + tid;
                int nn = c >> 4, off = (c & 15) << 3;
                *(uint4*)(sWT + nn * 136 + off) = *(const uint4*)(WvT + nn * 128 + off);
            }
        }
        __syncthreads();
#pragma unroll
        for (int q = 0; q < 4; ++q) {
            int c = q * 512 + tid;
            int r = c >> 4, off = (c & 15) << 3;
            int m = n0 + r;
            if (m < N_NODES)
                *(uint4*)(out + (size_t)m * HID + off) = *(const uint4*)(sH + r * 136 + off);
        }
    }
}

// ---- D7 fused: roles INTERLEAVED by blockIdx%2: scatter2 (latency) with
//      mm2/expand2 (compute). grid = 2*978. ----
__global__ __launch_bounds__(512, 4) void mm2_build2_kernel(const ushort* __restrict__ in,
                                                            const unsigned* __restrict__ aggin,
                                                            const int* __restrict__ cntin,
                                                            const float* __restrict__ baddin,
                                                            ushort* __restrict__ xout,
                                                            const ushort* __restrict__ WuT,
                                                            const ushort* __restrict__ WvT,
                                                            const float* __restrict__ bv,
                                                            ushort* __restrict__ outu,
                                                            ushort* __restrict__ outv,
                                                            const int* __restrict__ src2,
                                                            const int* __restrict__ dst2,
                                                            const int* __restrict__ cnt2,
                                                            const int* __restrict__ cursor2,
                                                            const int* __restrict__ partials2,
                                                            const int* __restrict__ seq,
                                                            int* __restrict__ srcS,
                                                            int* __restrict__ dstS,
                                                            unsigned* __restrict__ agg2) {
    __shared__ ushort sH[128 * 136];    // A-tile, then reused for D-restage
    __shared__ ushort sWT[128 * 136];   // Wu, then Wv
    int blk = blockIdx.x;
    int tid = threadIdx.x;

    int r2 = blk & 1, q2 = blk >> 1;
    if (r2 == 0) {   // latency pool: scatter src (layer 2, atomic-free)
        if (q2 >= BH_G) return;
        int e = q2 * 512 + tid;
        if (e >= N_EDGES) return;
        int idx = dst2[e];
        int pos = cursor2[idx] + partials2[idx >> 8] + seq[N_EDGES + e];
        srcS[N_EDGES + pos] = src2[e];
        return;
    }
    int ci = q2;   // compute pool: mm2 then expand2
    if (ci >= MM_G) {
        int gid = (ci - MM_G) * 512 + tid;
        if (gid >= N_NODES) return;
        int c = cnt2[gid];
        if (c == 0) return;
        int o = cursor2[gid] + partials2[gid >> 8];   // local in [0,N_EDGES)
        for (int i = 0; i < c; ++i) dstS[N_EDGES + o + i] = gid;
        bool spans = (o >> 4) != ((o + c - 1) >> 4);
        bool tail = (o + c == N_EDGES);
        if (spans || tail) {
            uint4* ap = (uint4*)(agg2 + (size_t)gid * HID);
#pragma unroll
            for (int i = 0; i < 32; ++i) ap[i] = make_uint4(0u, 0u, 0u, 0u);
        }
        return;
    }

    // ---- mm2 with fused layer-1 combine ----
    int n0 = ci * 128;
#pragma unroll
    for (int q = 0; q < 4; ++q) {
        int c = q * 512 + tid;
        int r = c >> 4, off = (c & 15) << 3;
        int n = n0 + r;
        uint4 vv = make_uint4(0, 0, 0, 0);
        if (n < N_NODES) {
            uint4 hv = *(const uint4*)(in + (size_t)n * HID + off);
            float add[8];
#pragma unroll
            for (int p = 0; p < 8; ++p) add[p] = 0.f;
            if (cntin[n] > 0) {
                uint4 e0 = *(const uint4*)(aggin + (size_t)n * HID + off);
                uint4 e1 = *(const uint4*)(aggin + (size_t)n * HID + off + 4);
                float4 bb0 = *(const float4*)(baddin + off);
                float4 bb1 = *(const float4*)(baddin + off + 4);
                add[0] = decf(e0.x) + bb0.x; add[1] = decf(e0.y) + bb0.y;
                add[2] = decf(e0.z) + bb0.z; add[3] = decf(e0.w) + bb0.w;
                add[4] = decf(e1.x) + bb1.x; add[5] = decf(e1.y) + bb1.y;
                add[6] = decf(e1.z) + bb1.z; add[7] = decf(e1.w) + bb1.w;
            }
            unsigned hw[4] = {hv.x, hv.y, hv.z, hv.w};
            unsigned ow[4];
#pragma unroll
            for (int p = 0; p < 4; ++p) {
                float lo = __uint_as_float(hw[p] << 16);
                float hi = __uint_as_float(hw[p] & 0xffff0000u);
                float r0 = fmaxf(add[2 * p] + lo, 0.f);
                float r1 = fmaxf(add[2 * p + 1] + hi, 0.f);
                ow[p] = cvt_pk_bf16(r0, r1);
            }
            vv = make_uint4(ow[0], ow[1], ow[2], ow[3]);
            *(uint4*)(xout + (size_t)n * HID + off) = vv;
        }
        *(uint4*)(sH + r * 136 + off) = vv;
    }
    // stage Wu
#pragma unroll
    for (int q = 0; q < 4; ++q) {
        int c = q * 512 + tid;
        int nn = c >> 4, off = (c & 15) << 3;
        *(uint4*)(sWT + nn * 136 + off) = *(const uint4*)(WuT + nn * 128 + off);
    }
    __syncthreads();

    int lane = tid & 63, wv = tid >> 6;
    int l15 = lane & 15, quad = lane >> 4;
    int ch = wv & 1, rh = wv >> 1;

    short8 afr[2][4];
#pragma unroll
    for (int rr = 0; rr < 2; ++rr) {
        const ushort* ab = sH + (rh * 32 + rr * 16 + l15) * 136 + quad * 8;
#pragma unroll
        for (int kc = 0; kc < 4; ++kc)
            afr[rr][kc] = *(const short8*)(ab + kc * 32);
    }

#pragma unroll
    for (int pass = 0; pass < 2; ++pass) {
        ushort* out = pass ? outv : outu;
        f32x4 acc[2][4];
#pragma unroll
        for (int rr = 0; rr < 2; ++rr)
#pragma unroll
            for (int ct = 0; ct < 4; ++ct) acc[rr][ct] = (f32x4){0.f, 0.f, 0.f, 0.f};
#pragma unroll
        for (int kc = 0; kc < 4; ++kc) {
#pragma unroll
            for (int ct = 0; ct < 4; ++ct) {
                short8 bfr = *(const short8*)(sWT + ((ch * 4 + ct) * 16 + l15) * 136 + quad * 8 + kc * 32);
                acc[0][ct] = __builtin_amdgcn_mfma_f32_16x16x32_bf16(afr[0][kc], bfr, acc[0][ct], 0, 0, 0);
                acc[1][ct] = __builtin_amdgcn_mfma_f32_16x16x32_bf16(afr[1][kc], bfr, acc[1][ct], 0, 0, 0);
            }
        }
        __syncthreads();   // sWT + sH(afr) reads done
#pragma unroll
        for (int ct = 0; ct < 4; ++ct) {
            int col = (ch * 4 + ct) * 16 + l15;
            float bb = pass ? bv[col] : 0.f;
#pragma unroll
            for (int rr = 0; rr < 2; ++rr) {
                int rowb = rh * 32 + rr * 16 + quad * 4;
                unsigned p01 = cvt_pk_bf16(acc[rr][ct][0] + bb, acc[rr][ct][1] + bb);
                unsigned p23 = cvt_pk_bf16(acc[rr][ct][2] + bb, acc[rr][ct][3] + bb);
                sH[(rowb + 0) * 136 + col] = (ushort)p01;
                sH[(rowb + 1) * 136 + col] = (ushort)(p01 >> 16);
                sH[(rowb + 2) * 136 + col] = (ushort)p23;
                sH[(rowb + 3) * 136 + col] = (ushort)(p23 >> 16);
            }
        }
        if (pass == 0) {   // restage Wv over sWT (reads drained by the barrier above)
#pragma unroll
            for (int q = 0; q < 4; ++q) {
                int c = q * 512 + tid;
                int nn = c >> 4, off = (c & 15) << 3;
                *(uint4*)(sWT + nn * 136 + off) = *(const uint4*)(WvT + nn * 128 + off);
            }
        }
        __syncthreads();
#pragma unroll
        for (int q = 0; q < 4; ++q) {
            int c = q * 512 + tid;
            int r = c >> 4, off = (c & 15) << 3;
            int m = n0 + r;
            if (m < N_NODES)
                *(uint4*)(out + (size_t)m * HID + off) = *(const uint4*)(sH + r * 136 + off);
        }
    }
}

// ---- edge conv: bf16 MFMA, 64-edge dst-sorted windows, 512 threads.
//      (R14 shape: cvt_pk_bf16 + bijective XCD-chunked swizzle.) ----
__global__ __launch_bounds__(512, 6) void edge_kernel(const ushort* __restrict__ u,
                                                      const ushort* __restrict__ v,
                                                      const float* __restrict__ xkey,
                                                      const int* __restrict__ srcS,
                                                      const int* __restrict__ dstS,
                                                      const ushort* __restrict__ WbT,
                                                      const float* __restrict__ wlast,
                                                      unsigned* __restrict__ agg) {
    __shared__ ushort sWT[128 * 136];   // 34816 B: WbT[n][k] bf16, padded stride
    __shared__ ushort sU[64 * 136];     // 17408 B union: t[64][136] then msgT[128][66]
    __shared__ int sDst[64];
    __shared__ int sBnd[2];             // [0]=dst before window, [1]=dst after window
    __shared__ unsigned sMask[3];       // head-flag mask lo/hi + head64 flag
    int tid = threadIdx.x;

    // bijective XCD chunking (nwg % 8 != 0 -> m204 variant)
    int nwg = gridDim.x;
    int orig = blockIdx.x;
    int qq = nwg >> 3, rr8 = nwg & 7;
    int xcd = orig & 7, idx = orig >> 3;
    int wgid = (xcd < rr8 ? xcd * (qq + 1) : rr8 * (qq + 1) + (xcd - rr8) * qq) + idx;
    int w0 = wgid * 64;

    // W stage: 2048 uint4 over 512 threads = 4 each (L2-hot 32KB)
#pragma unroll
    for (int q = 0; q < 4; ++q) {
        int c = q * 512 + tid;
        int n = c >> 4, off = (c & 15) << 3;
        *(uint4*)(sWT + n * 136 + off) = *(const uint4*)(WbT + n * 128 + off);
    }

    int eloc = tid >> 3;
    int sub = tid & 7;
    int kb = sub << 4;
    int lane = tid & 63, wv = tid >> 6;
    int l15 = lane & 15, quad = lane >> 4;
    int ch = wv & 1, rh = wv >> 1;

    // loop-invariant wlast slice for this thread's 16 columns -> registers
    float wreg[16];
    {
        const float4* wr4 = (const float4*)(wlast + kb);
#pragma unroll
        for (int q = 0; q < 4; ++q) {
            float4 wq = wr4[q];
            wreg[q * 4 + 0] = wq.x; wreg[q * 4 + 1] = wq.y;
            wreg[q * 4 + 2] = wq.z; wreg[q * 4 + 3] = wq.w;
        }
    }

    // phase 1: per-thread meta + gather + compute t
    {
        int e = w0 + eloc;
        if (e >= N_EDGES) e = N_EDGES - 1;   // clamp: idempotent under max
        int sx = srcS[e], sy = dstS[e];
        if (sub == 0) sDst[eloc] = sy;
        if (tid < 2) {
            int eb = (tid == 0) ? (w0 - 1) : (w0 + 64);
            sBnd[tid] = (eb >= 0 && eb < N_EDGES) ? dstS[eb] : -1;
        }
        float kd = xkey[sx] - xkey[sy];
        const uint4* ur = (const uint4*)(u + (size_t)sx * HID + kb);
        const uint4* vr = (const uint4*)(v + (size_t)sy * HID + kb);
        uint4 uu[2], vvv[2];
        uu[0] = ur[0]; uu[1] = ur[1];
        vvv[0] = vr[0]; vvv[1] = vr[1];
#pragma unroll
        for (int q = 0; q < 2; ++q) {
            unsigned pu[4] = {uu[q].x, uu[q].y, uu[q].z, uu[q].w};
            unsigned pv[4] = {vvv[q].x, vvv[q].y, vvv[q].z, vvv[q].w};
            unsigned pk[4];
#pragma unroll
            for (int p = 0; p < 4; ++p) {
                float a0 = __uint_as_float(pu[p] << 16) + __uint_as_float(pv[p] << 16);
                float a1 = __uint_as_float(pu[p] & 0xffff0000u) + __uint_as_float(pv[p] & 0xffff0000u);
                a0 = fmaf(kd, wreg[q * 8 + 2 * p], a0);
                a1 = fmaf(kd, wreg[q * 8 + 2 * p + 1], a1);
                a0 = fmaxf(a0, 0.1f * a0);   // leaky relu
                a1 = fmaxf(a1, 0.1f * a1);
                pk[p] = cvt_pk_bf16(a0, a1);
            }
            uint4 o; o.x = pk[0]; o.y = pk[1]; o.z = pk[2]; o.w = pk[3];
            *(uint4*)(sU + eloc * 136 + kb + q * 8) = o;
        }
    }
    __syncthreads();   // W-stage + t + sDst + sBnd ready

    // segment head flags: computed ONCE by wave 0 (uniform across columns)
    if (tid < 64) {
        int dprev = (tid == 0) ? sBnd[0] : sDst[tid - 1];
        unsigned long long m = __ballot(sDst[tid] != dprev);
        if (tid == 0) { sMask[0] = (unsigned)m; sMask[1] = (unsigned)(m >> 32); }
        if (tid == 63) sMask[2] = (sDst[63] != sBnd[1]) ? 1u : 0u;
    }

    // phase 2: MFMA. wave wv: rows (wv>>1)*16..+15, cols (wv&1)*64..+63
    short8 afr[4];
    {
        const ushort* ab = sU + (rh * 16 + l15) * 136 + quad * 8;
#pragma unroll
        for (int kc = 0; kc < 4; ++kc)
            afr[kc] = *(const short8*)(ab + kc * 32);
    }
    f32x4 acc[4];
#pragma unroll
    for (int ct = 0; ct < 4; ++ct) acc[ct] = (f32x4){0.f, 0.f, 0.f, 0.f};
#pragma unroll
    for (int kc = 0; kc < 4; ++kc) {
#pragma unroll
        for (int ct = 0; ct < 4; ++ct) {
            short8 bfr = *(const short8*)(sWT + ((ch * 4 + ct) * 16 + l15) * 136 + quad * 8 + kc * 32);
            acc[ct] = __builtin_amdgcn_mfma_f32_16x16x32_bf16(afr[kc], bfr, acc[ct], 0, 0, 0);
        }
    }
    __syncthreads();   // all t reads done -> sU reusable

    // epilogue: msgT[col][edge] bf16, stride 66 (odd dword stride -> conflict-free)
#pragma unroll
    for (int ct = 0; ct < 4; ++ct) {
        int col = (ch * 4 + ct) * 16 + l15;
        uint2 pr;
        pr.x = cvt_pk_bf16(acc[ct][0], acc[ct][1]);
        pr.y = cvt_pk_bf16(acc[ct][2], acc[ct][3]);
        *(uint2*)(sU + col * 66 + rh * 16 + quad * 4) = pr;
    }
    __syncthreads();

    // phase 3: mask-driven segmented max, 4 threads/col (16 edges each).
    {
        int j = tid & 127;
        int q4 = tid >> 7;            // 0..3 (wave-uniform)
        int base = q4 * 16;
        const ushort* mrow = sU + j * 66 + base;
        float vals[16];
#pragma unroll
        for (int q = 0; q < 4; ++q) {
            ushort4 mv = *(const ushort4*)(mrow + q * 4);
            vals[q * 4 + 0] = bf2f(mv.x);
            vals[q * 4 + 1] = bf2f(mv.y);
            vals[q * 4 + 2] = bf2f(mv.z);
            vals[q * 4 + 3] = bf2f(mv.w);
        }
        unsigned mlo = __builtin_amdgcn_readfirstlane(sMask[0]);
        unsigned mhi = __builtin_amdgcn_readfirstlane(sMask[1]);
        unsigned b64 = __builtin_amdgcn_readfirstlane(sMask[2]);
        unsigned long long mask = ((unsigned long long)mhi << 32) | mlo;
        unsigned slice = (unsigned)((mask >> base) & 0xFFFFull);
        unsigned nextbit = (q4 == 3) ? (b64 & 1u) : (unsigned)((mask >> (base + 16)) & 1ull);
        unsigned ext = slice | (nextbit << 16);
        bool contFrom = !(ext & 1u);
        float run = 0.f;
        bool first = true;
#pragma unroll
        for (int e3 = 0; e3 < 16; ++e3) {
            float vv2 = vals[e3];
            bool hb = (ext >> e3) & 1u;
            run = (e3 == 0 || hb) ? vv2 : fmaxf(run, vv2);
            bool end = (e3 == 15) || ((ext >> (e3 + 1)) & 1u);
            if (end) {
                int d = sDst[base + e3];
                unsigned en = encf(run);
                unsigned* ap = agg + (size_t)d * HID + j;
                bool useAtomic = (first && contFrom) || ((e3 == 15) && !nextbit);
                if (useAtomic) atomicMax(ap, en);
                else *ap = en;
                first = false;
            }
        }
    }
}

// ---- pooling with fused layer-2 combine: x2 never materialized; 16 slices/graph ----
__global__ __launch_bounds__(256) void pool_kernel(const ushort* __restrict__ x1,
                                                   const unsigned* __restrict__ agg2,
                                                   const float* __restrict__ b2b,
                                                   const int* __restrict__ cnt2,
                                                   const int* __restrict__ batch,
                                                   float* __restrict__ pooled) {
    int g = blockIdx.x >> 4, s = blockIdx.x & 15;
    int tid = threadIdx.x;
    int lo = 0, hi = N_NODES;
    while (lo < hi) { int mid = (lo + hi) >> 1; if (batch[mid] < g) lo = mid + 1; else hi = mid; }
    int start = lo;
    hi = N_NODES;
    while (lo < hi) { int mid = (lo + hi) >> 1; if (batch[mid] < g + 1) lo = mid + 1; else hi = mid; }
    int end = lo;
    int cnt = end - start;
    int b0 = start + (int)((long long)cnt * s / 16);
    int b1 = start + (int)((long long)cnt * (s + 1) / 16);
    if (b1 <= b0) return;
    int j = tid & 127;
    bool isx2 = tid >= 128;
    float bbj = isx2 ? b2b[j] : 0.f;
    float mx = -INFINITY, sm = 0.f;
    for (int n = b0; n < b1; ++n) {
        float xv = bf2f(x1[(size_t)n * HID + j]);
        float vv;
        if (isx2) {
            float a = 0.f;
            if (cnt2[n] > 0) a = decf(agg2[(size_t)n * HID + j]) + bbj;
            vv = fmaxf(a + xv, 0.f);
        } else {
            vv = xv;
        }
        mx = fmaxf(mx, vv);
        sm += vv;
    }
    atomicMax((unsigned*)pooled + (size_t)g * 512 + tid, encf(mx));
    atomicAdd(pooled + (size_t)g * 512 + 256 + tid, sm);
}

// ---- final MLP + log_softmax ----
__global__ __launch_bounds__(128) void final_kernel(const float* __restrict__ pooled,
                                                    const int* __restrict__ batch,
                                                    const float* __restrict__ Wf1,
                                                    const float* __restrict__ bf1,
                                                    const float* __restrict__ Wf2,
                                                    const float* __restrict__ bf2,
                                                    float* __restrict__ out) {
    __shared__ float sP[512];
    __shared__ float sH[128];
    int g = blockIdx.x, tid = threadIdx.x;
    int lo = 0, hi = N_NODES;
    while (lo < hi) { int mid = (lo + hi) >> 1; if (batch[mid] < g) lo = mid + 1; else hi = mid; }
    int start = lo;
    hi = N_NODES;
    while (lo < hi) { int mid = (lo + hi) >> 1; if (batch[mid] < g + 1) lo = mid + 1; else hi = mid; }
    int cnt = lo - start;
    float inv = 1.f / (float)(cnt > 1 ? cnt : 1);
#pragma unroll
    for (int q = 0; q < 4; ++q) {
        int idx = q * 128 + tid;
        float raw;
        if (idx < 256) {
            unsigned e = ((const unsigned*)pooled)[(size_t)g * 512 + idx];
            raw = (e == 0u) ? 0.f : decf(e);
        } else {
            raw = pooled[(size_t)g * 512 + idx] * inv;
        }
        sP[idx] = raw;
    }
    __syncthreads();
    float acc = bf1[tid];
    for (int k = 0; k < 512; ++k) acc = fmaf(sP[k], Wf1[k * HID + tid], acc);
    sH[tid] = fmaxf(acc, 0.f);
    __syncthreads();
    if (tid < 2) {
        float l = bf2[tid];
        for (int k = 0; k < 128; ++k) l = fmaf(sH[k], Wf2[k * 2 + tid], l);
        sP[tid] = l;
    }
    __syncthreads();
    if (tid == 0) {
        float l0 = sP[0], l1 = sP[1];
        float m = fmaxf(l0, l1);
        float ls = m + logf(expf(l0 - m) + expf(l1 - m));
        out[g * 2 + 0] = l0 - ls;
        out[g * 2 + 1] = l1 - ls;
    }
}

extern "C" void kernel_launch(void* const* d_in, const int* in_sizes, int n_in,
                              void* d_out, int out_size, void* d_ws, size_t ws_size,
                              hipStream_t stream) {
    const float* x     = (const float*)d_in[0];
    const float* W_enc = (const float*)d_in[1];
    const float* b_enc = (const float*)d_in[2];
    const float* W0    = (const float*)d_in[3];
    const float* b0    = (const float*)d_in[4];
    const float* W1a   = (const float*)d_in[5];
    const float* b1a   = (const float*)d_in[6];
    const float* W1b   = (const float*)d_in[7];
    const float* b1b   = (const float*)d_in[8];
    const float* W2a   = (const float*)d_in[9];
    const float* b2a   = (const float*)d_in[10];
    const float* W2b   = (const float*)d_in[11];
    const float* b2b   = (const float*)d_in[12];
    const float* Wf1   = (const float*)d_in[13];
    const float* bf1   = (const float*)d_in[14];
    const float* Wf2   = (const float*)d_in[15];
    const float* bf2   = (const float*)d_in[16];
    const int* src1    = (const int*)d_in[17];
    const int* dst1    = (const int*)d_in[18];
    const int* src2    = (const int*)d_in[19];
    const int* dst2    = (const int*)d_in[20];
    const int* batch   = (const int*)d_in[21];

    const size_t NB = (size_t)N_NODES * HID;     // 12.8M elements
    ushort* hbuf  = (ushort*)d_ws;               // h -> x1 (in place, bf16)
    unsigned* agg1 = (unsigned*)(hbuf + NB);     // layer-1 segment-max (u32 encoded)
    unsigned* agg2 = agg1 + NB;                  // layer-2 segment-max
    ushort* ubuf  = (ushort*)(agg2 + NB);        // u bf16
    ushort* vbuf  = ubuf + NB;                   // v bf16
    ushort* WT    = vbuf + NB;                   // 6 x 16384 bf16: Wb1,Wb2,Wu1,Wv1,Wu2,Wv2
    ushort* WbT1 = WT;
    ushort* WbT2 = WT + 1 * HID * HID;
    ushort* WuT1 = WT + 2 * HID * HID;
    ushort* WvT1 = WT + 3 * HID * HID;
    ushort* WuT2 = WT + 4 * HID * HID;
    ushort* WvT2 = WT + 5 * HID * HID;
    float* wkey  = (float*)(WT + 6 * HID * HID);
    float* bias0 = wkey + 128;
    float* xkey  = bias0 + 128;                  // dense per-node key (N_NODES fp32)
    float* pooled = xkey + N_NODES;              // 128*512 fp32
    int* cnt    = (int*)(pooled + 128 * 512);    // 2*N_NODES bucket totals (layer1 | layer2)
    int* cursor = cnt + 2 * N_NODES;             // 2*N_NODES local-exclusive (layer1 | layer2)
    int* partials1 = cursor + 2 * N_NODES;       // 512
    int* partials2 = partials1 + 512;            // 512
    int* srcS = partials2 + 512;                 // 2*N_EDGES sorted src
    int* dstS = srcS + 2 * N_EDGES;              // 2*N_EDGES sorted dst (dense expand)
    int* seq  = dstS + 2 * N_EDGES;              // 2*N_EDGES within-bucket rank

    const int edgeGrid = (N_EDGES + 63) / 64;          // 7813 windows of 64
    const int prepGrid = E256_G + 385 + 256;           // hist1 + transpose+prep+zero
    const int buildMmGrid = 3 * (MM_G + AH_G);         // 2934: interleaved 2 lat : 1 comp
    const int mm2Grid = 2 * (MM_G + AH_G);             // 1956: interleaved 1 lat : 1 comp

    hipMemsetAsync(cnt, 0, 2 * N_NODES * sizeof(int), stream);
    prep_hist_kernel<<<prepGrid, 256, 0, stream>>>(W1b, W2b, W1a, W2a, W_enc, b_enc, W0, b0,
                                                   WT, wkey, bias0, pooled, dst1, cnt, seq);
    scan_half_kernel<<<SCANH_B, 256, 0, stream>>>(cnt, cursor, partials1);
    scan2_half_kernel<<<1, 512, 0, stream>>>(partials1);

    // ---- fused (interleaved): hist2 || scatter1 || mm1(enc) || expand1 ----
    build_mm_kernel<<<buildMmGrid, 512, 0, stream>>>(x, W0, wkey, bias0, hbuf, xkey,
                                                     WuT1, WvT1, b1a, ubuf, vbuf,
                                                     src1, dst1, dst2, cnt, cursor, partials1,
                                                     cnt + N_NODES, seq, srcS, dstS, agg1);

    // ---- layer-2 scan (tiny; inputs ready from hist2 above) ----
    scan_half_kernel<<<SCANH_B, 256, 0, stream>>>(cnt + N_NODES, cursor + N_NODES, partials2);
    scan2_half_kernel<<<1, 512, 0, stream>>>(partials2);

    // ---- layer 1 edge ----
    edge_kernel<<<edgeGrid, 512, 0, stream>>>(ubuf, vbuf, xkey, srcS, dstS, WbT1,
                                              W1a + 256 * HID, agg1);

    // ---- fused (interleaved): scatter2 || mm2 (layer-1 combine) || expand2 ----
    mm2_build2_kernel<<<mm2Grid, 512, 0, stream>>>(hbuf, agg1, cnt, b1b, hbuf,
                                                   WuT2, WvT2, b2a, ubuf, vbuf,
                                                   src2, dst2, cnt + N_NODES, cursor + N_NODES,
                                                   partials2, seq, srcS, dstS, agg2);
    edge_kernel<<<edgeGrid, 512, 0, stream>>>(ubuf, vbuf, xkey, srcS + N_EDGES, dstS + N_EDGES,
                                              WbT2, W2a + 256 * HID, agg2);

    // ---- pooling (layer-2 combine fused; pooled zeroed by prep_hist) + head ----
    pool_kernel<<<N_GRAPHS * 16, 256, 0, stream>>>(hbuf, agg2, b2b, cnt + N_NODES, batch, pooled);
    final_kernel<<<N_GRAPHS, 128, 0, stream>>>(pooled, batch, Wf1, bf1, Wf2, bf2, (float*)d_out);
}

// Round 18
// 439.169 us; speedup vs baseline: 1.0553x; 1.0553x over previous
//
#include <hip/hip_runtime.h>
#include <cstdint>

#define N_NODES 100000
#define N_EDGES 500000
#define N_GRAPHS 128
#define HID 128
#define SCANH_B ((N_NODES + 255) / 256)       // 391 blocks per-layer scan
#define E256_G ((N_EDGES + 255) / 256)        // 1954 hist blocks (256 thr)
#define MM_G ((N_NODES + 127) / 128)          // 782 mm blocks
#define AH_G ((N_NODES + 511) / 512)          // 196 expand/zbound blocks (512 thr)
#define BH_G ((N_EDGES + 511) / 512)          // 977 scatter / hist blocks (512 thr)
#define EDGE_G ((N_EDGES + 63) / 64)          // 7813 edge windows

typedef __attribute__((ext_vector_type(8))) short short8;
typedef __attribute__((ext_vector_type(4))) float f32x4;

// ---- monotone float<->uint encoding for max; enc==0 marks "never written" ----
__device__ __forceinline__ unsigned encf(float f) {
    unsigned u = __float_as_uint(f);
    return (u & 0x80000000u) ? ~u : (u | 0x80000000u);
}
__device__ __forceinline__ float decf(unsigned e) {
    unsigned u = (e & 0x80000000u) ? (e & 0x7FFFFFFFu) : ~e;
    return __uint_as_float(u);
}
// ---- hardware packed f32->bf16 (RNE, src0->low half). absmax 0.0078125 vs
//      manual round (1 bf16 ULP), accepted since R14; numerics frozen. ----
__device__ __forceinline__ unsigned cvt_pk_bf16(float lo, float hi) {
    unsigned r;
    asm("v_cvt_pk_bf16_f32 %0, %1, %2" : "=v"(r) : "v"(lo), "v"(hi));
    return r;
}
__device__ __forceinline__ ushort bf16r(float f) {
    unsigned u = __float_as_uint(f);
    return (ushort)((u + 0x7fffu + ((u >> 16) & 1u)) >> 16);
}
__device__ __forceinline__ float bf2f(ushort h) {
    return __uint_as_float((unsigned)h << 16);
}

// ---- D1: HIST LAYER 1 + transpose weights + prep + zero pooled. ----
__global__ __launch_bounds__(256) void prep_hist_kernel(const float* __restrict__ W1b,
                                                        const float* __restrict__ W2b,
                                                        const float* __restrict__ W1a,
                                                        const float* __restrict__ W2a,
                                                        const float* __restrict__ W_enc,
                                                        const float* __restrict__ b_enc,
                                                        const float* __restrict__ W0,
                                                        const float* __restrict__ b0,
                                                        ushort* __restrict__ WT,
                                                        float* __restrict__ wkey,
                                                        float* __restrict__ bias0,
                                                        float* __restrict__ pooled,
                                                        const int* __restrict__ dst1,
                                                        int* __restrict__ cnt,
                                                        int* __restrict__ seq) {
    int blk = blockIdx.x;
    int tid = threadIdx.x;
    if (blk < E256_G) {   // hist layer 1
        int e = blk * 256 + tid;
        if (e < N_EDGES) seq[e] = atomicAdd(&cnt[dst1[e]], 1);
        return;
    }
    int b2 = blk - E256_G;
    if (b2 < 384) {   // weight transpose
        int m = b2 >> 6;
        int i = (b2 & 63) * 256 + tid;   // i = n*128 + k
        int n = i >> 7, k = i & 127;
        int src = k * HID + n;
        float v;
        switch (m) {
            case 0: v = W1b[src]; break;
            case 1: v = W2b[src]; break;
            case 2: v = W1a[src]; break;
            case 3: v = W1a[HID * HID + src] - W1a[src]; break;
            case 4: v = W2a[src]; break;
            default: v = W2a[HID * HID + src] - W2a[src]; break;
        }
        WT[m * HID * HID + i] = bf16r(v);
        return;
    }
    if (b2 == 384) {   // prep
        if (tid < HID) {
            float wk = 0.f, bk = b0[tid];
            for (int k = 0; k < 32; ++k) {
                float w = W0[(15 + k) * HID + tid];
                wk += W_enc[k] * w;
                bk += b_enc[k] * w;
            }
            wkey[tid] = wk;
            bias0[tid] = bk;
        }
        return;
    }
    // zero pooled (exactly 256*256 = 65536 floats)
    pooled[(b2 - 385) * 256 + tid] = 0.f;
}

// ---- per-layer scan (N_NODES items): local-exclusive cursor + partials ----
__global__ __launch_bounds__(256) void scan_half_kernel(const int* __restrict__ cnt,
                                                        int* __restrict__ cursor,
                                                        int* __restrict__ partials) {
    __shared__ int tmp[256];
    int tid = threadIdx.x;
    int gid = blockIdx.x * 256 + tid;
    int v = (gid < N_NODES) ? cnt[gid] : 0;
    tmp[tid] = v;
    __syncthreads();
#pragma unroll
    for (int off = 1; off < 256; off <<= 1) {
        int t = (tid >= off) ? tmp[tid - off] : 0;
        __syncthreads();
        tmp[tid] += t;
        __syncthreads();
    }
    if (gid < N_NODES) cursor[gid] = tmp[tid] - v;   // local exclusive
    if (tid == 255) partials[blockIdx.x] = tmp[255];
}

__global__ __launch_bounds__(512) void scan2_half_kernel(int* __restrict__ partials) {
    __shared__ int tmp[512];
    int tid = threadIdx.x;
    int v = (tid < SCANH_B) ? partials[tid] : 0;
    tmp[tid] = v;
    __syncthreads();
#pragma unroll
    for (int off = 1; off < 512; off <<= 1) {
        int t = (tid >= off) ? tmp[tid - off] : 0;
        __syncthreads();
        tmp[tid] += t;
        __syncthreads();
    }
    if (tid < SCANH_B) partials[tid] = tmp[tid] - v;  // exclusive
}

// ---- D4 fused: [mm1 w/ inline encode] + [expand1] + [scatter1].
//      (hist2 moved into edge1's dispatch, where 7813 compute blocks
//      outnumber its 977 latency blocks 8:1 — R17 showed overlap fails
//      when latency blocks dominate the resident set.) ----
__global__ __launch_bounds__(512, 4) void build_mm_kernel(const float* __restrict__ x,
                                                          const float* __restrict__ W0,
                                                          const float* __restrict__ wkey,
                                                          const float* __restrict__ bias0,
                                                          ushort* __restrict__ h,
                                                          float* __restrict__ xkey,
                                                          const ushort* __restrict__ WuT,
                                                          const ushort* __restrict__ WvT,
                                                          const float* __restrict__ bv,
                                                          ushort* __restrict__ outu,
                                                          ushort* __restrict__ outv,
                                                          const int* __restrict__ src1,
                                                          const int* __restrict__ dst1,
                                                          const int* __restrict__ cnt,
                                                          const int* __restrict__ cursor,
                                                          const int* __restrict__ partials1,
                                                          const int* __restrict__ seq,
                                                          int* __restrict__ srcS,
                                                          int* __restrict__ dstS,
                                                          unsigned* __restrict__ agg1) {
    __shared__ ushort sH[128 * 136];    // A-tile, then reused for D-restage
    __shared__ ushort sWT[128 * 136];   // Wu, then Wv
    int blk = blockIdx.x;
    int tid = threadIdx.x;

    if (blk >= MM_G) {
        int zb = blk - MM_G;
        if (zb < AH_G) {   // expand dst (layer 1) + zero boundary agg1 rows
            int gid = zb * 512 + tid;
            if (gid >= N_NODES) return;
            int c = cnt[gid];
            if (c == 0) return;
            int o = cursor[gid] + partials1[gid >> 8];
            for (int i = 0; i < c; ++i) dstS[o + i] = gid;
            bool spans = (o >> 4) != ((o + c - 1) >> 4);
            bool tail = (o + c == N_EDGES);
            if (spans || tail) {
                uint4* ap = (uint4*)(agg1 + (size_t)gid * HID);
#pragma unroll
                for (int i = 0; i < 32; ++i) ap[i] = make_uint4(0u, 0u, 0u, 0u);
            }
            return;
        }
        {   // scatter src (layer 1, atomic-free)
            int e = (zb - AH_G) * 512 + tid;
            if (e >= N_EDGES) return;
            int idx = dst1[e];
            int pos = cursor[idx] + partials1[idx >> 8] + seq[e];
            srcS[pos] = src1[e];
            return;
        }
    }

    // ---- mm1 with inline encode ----
    int n0 = blk * 128;
#pragma unroll
    for (int q = 0; q < 4; ++q) {
        int c = q * 512 + tid;
        int r = c >> 4, off = (c & 15) << 3;
        int n = n0 + r;
        uint4 vv = make_uint4(0, 0, 0, 0);
        if (n < N_NODES) {
            const float* xr = x + n * 16;
            float k0 = xr[0];
            if (off == 0) xkey[n] = k0;
            float xf[15];
#pragma unroll
            for (int f = 0; f < 15; ++f) xf[f] = xr[1 + f];
            unsigned ow[4];
#pragma unroll
            for (int p = 0; p < 4; ++p) {
                int c0 = off + 2 * p;
                float a0 = bias0[c0] + k0 * wkey[c0];
                float a1 = bias0[c0 + 1] + k0 * wkey[c0 + 1];
#pragma unroll
                for (int f = 0; f < 15; ++f) {
                    float2 w2 = *(const float2*)(W0 + f * HID + c0);
                    a0 = fmaf(xf[f], w2.x, a0);
                    a1 = fmaf(xf[f], w2.y, a1);
                }
                ow[p] = cvt_pk_bf16(fmaxf(a0, 0.f), fmaxf(a1, 0.f));
            }
            vv = make_uint4(ow[0], ow[1], ow[2], ow[3]);
            *(uint4*)(h + (size_t)n * HID + off) = vv;
        }
        *(uint4*)(sH + r * 136 + off) = vv;
    }
    // stage Wu
#pragma unroll
    for (int q = 0; q < 4; ++q) {
        int c = q * 512 + tid;
        int nn = c >> 4, off = (c & 15) << 3;
        *(uint4*)(sWT + nn * 136 + off) = *(const uint4*)(WuT + nn * 128 + off);
    }
    __syncthreads();

    int lane = tid & 63, wv = tid >> 6;
    int l15 = lane & 15, quad = lane >> 4;
    int ch = wv & 1, rh = wv >> 1;

    short8 afr[2][4];
#pragma unroll
    for (int rr = 0; rr < 2; ++rr) {
        const ushort* ab = sH + (rh * 32 + rr * 16 + l15) * 136 + quad * 8;
#pragma unroll
        for (int kc = 0; kc < 4; ++kc)
            afr[rr][kc] = *(const short8*)(ab + kc * 32);
    }

#pragma unroll
    for (int pass = 0; pass < 2; ++pass) {
        ushort* out = pass ? outv : outu;
        f32x4 acc[2][4];
#pragma unroll
        for (int rr = 0; rr < 2; ++rr)
#pragma unroll
            for (int ct = 0; ct < 4; ++ct) acc[rr][ct] = (f32x4){0.f, 0.f, 0.f, 0.f};
#pragma unroll
        for (int kc = 0; kc < 4; ++kc) {
#pragma unroll
            for (int ct = 0; ct < 4; ++ct) {
                short8 bfr = *(const short8*)(sWT + ((ch * 4 + ct) * 16 + l15) * 136 + quad * 8 + kc * 32);
                acc[0][ct] = __builtin_amdgcn_mfma_f32_16x16x32_bf16(afr[0][kc], bfr, acc[0][ct], 0, 0, 0);
                acc[1][ct] = __builtin_amdgcn_mfma_f32_16x16x32_bf16(afr[1][kc], bfr, acc[1][ct], 0, 0, 0);
            }
        }
        __syncthreads();   // sWT + sH(afr) reads done
#pragma unroll
        for (int ct = 0; ct < 4; ++ct) {
            int col = (ch * 4 + ct) * 16 + l15;
            float bb = pass ? bv[col] : 0.f;
#pragma unroll
            for (int rr = 0; rr < 2; ++rr) {
                int rowb = rh * 32 + rr * 16 + quad * 4;
                unsigned p01 = cvt_pk_bf16(acc[rr][ct][0] + bb, acc[rr][ct][1] + bb);
                unsigned p23 = cvt_pk_bf16(acc[rr][ct][2] + bb, acc[rr][ct][3] + bb);
                sH[(rowb + 0) * 136 + col] = (ushort)p01;
                sH[(rowb + 1) * 136 + col] = (ushort)(p01 >> 16);
                sH[(rowb + 2) * 136 + col] = (ushort)p23;
                sH[(rowb + 3) * 136 + col] = (ushort)(p23 >> 16);
            }
        }
        if (pass == 0) {   // restage Wv over sWT (reads drained by the barrier above)
#pragma unroll
            for (int q = 0; q < 4; ++q) {
                int c = q * 512 + tid;
                int nn = c >> 4, off = (c & 15) << 3;
                *(uint4*)(sWT + nn * 136 + off) = *(const uint4*)(WvT + nn * 128 + off);
            }
        }
        __syncthreads();
#pragma unroll
        for (int q = 0; q < 4; ++q) {
            int c = q * 512 + tid;
            int r = c >> 4, off = (c & 15) << 3;
            int m = n0 + r;
            if (m < N_NODES)
                *(uint4*)(out + (size_t)m * HID + off) = *(const uint4*)(sH + r * 136 + off);
        }
    }
}

// ---- D7 fused: [scatter2] + [expand2] + [mm2 (layer-1 combine)] (R16 layout) ----
__global__ __launch_bounds__(512, 4) void mm2_build2_kernel(const ushort* __restrict__ in,
                                                            const unsigned* __restrict__ aggin,
                                                            const int* __restrict__ cntin,
                                                            const float* __restrict__ baddin,
                                                            ushort* __restrict__ xout,
                                                            const ushort* __restrict__ WuT,
                                                            const ushort* __restrict__ WvT,
                                                            const float* __restrict__ bv,
                                                            ushort* __restrict__ outu,
                                                            ushort* __restrict__ outv,
                                                            const int* __restrict__ src2,
                                                            const int* __restrict__ dst2,
                                                            const int* __restrict__ cnt2,
                                                            const int* __restrict__ cursor2,
                                                            const int* __restrict__ partials2,
                                                            const int* __restrict__ seq,
                                                            int* __restrict__ srcS,
                                                            int* __restrict__ dstS,
                                                            unsigned* __restrict__ agg2) {
    __shared__ ushort sH[128 * 136];    // A-tile, then reused for D-restage
    __shared__ ushort sWT[128 * 136];   // Wu, then Wv
    int blk = blockIdx.x;
    int tid = threadIdx.x;

    if (blk < BH_G) {   // scatter src (layer 2, atomic-free)
        int e = blk * 512 + tid;
        if (e >= N_EDGES) return;
        int idx = dst2[e];
        int pos = cursor2[idx] + partials2[idx >> 8] + seq[N_EDGES + e];
        srcS[N_EDGES + pos] = src2[e];
        return;
    }
    int b = blk - BH_G;
    if (b < AH_G) {   // expand dst (layer 2, local positions) + zero boundary agg2 rows
        int gid = b * 512 + tid;
        if (gid >= N_NODES) return;
        int c = cnt2[gid];
        if (c == 0) return;
        int o = cursor2[gid] + partials2[gid >> 8];   // local in [0,N_EDGES)
        for (int i = 0; i < c; ++i) dstS[N_EDGES + o + i] = gid;
        bool spans = (o >> 4) != ((o + c - 1) >> 4);
        bool tail = (o + c == N_EDGES);
        if (spans || tail) {
            uint4* ap = (uint4*)(agg2 + (size_t)gid * HID);
#pragma unroll
            for (int i = 0; i < 32; ++i) ap[i] = make_uint4(0u, 0u, 0u, 0u);
        }
        return;
    }

    // ---- mm2 with fused layer-1 combine ----
    int n0 = (b - AH_G) * 128;
#pragma unroll
    for (int q = 0; q < 4; ++q) {
        int c = q * 512 + tid;
        int r = c >> 4, off = (c & 15) << 3;
        int n = n0 + r;
        uint4 vv = make_uint4(0, 0, 0, 0);
        if (n < N_NODES) {
            uint4 hv = *(const uint4*)(in + (size_t)n * HID + off);
            float add[8];
#pragma unroll
            for (int p = 0; p < 8; ++p) add[p] = 0.f;
            if (cntin[n] > 0) {
                uint4 e0 = *(const uint4*)(aggin + (size_t)n * HID + off);
                uint4 e1 = *(const uint4*)(aggin + (size_t)n * HID + off + 4);
                float4 bb0 = *(const float4*)(baddin + off);
                float4 bb1 = *(const float4*)(baddin + off + 4);
                add[0] = decf(e0.x) + bb0.x; add[1] = decf(e0.y) + bb0.y;
                add[2] = decf(e0.z) + bb0.z; add[3] = decf(e0.w) + bb0.w;
                add[4] = decf(e1.x) + bb1.x; add[5] = decf(e1.y) + bb1.y;
                add[6] = decf(e1.z) + bb1.z; add[7] = decf(e1.w) + bb1.w;
            }
            unsigned hw[4] = {hv.x, hv.y, hv.z, hv.w};
            unsigned ow[4];
#pragma unroll
            for (int p = 0; p < 4; ++p) {
                float lo = __uint_as_float(hw[p] << 16);
                float hi = __uint_as_float(hw[p] & 0xffff0000u);
                float r0 = fmaxf(add[2 * p] + lo, 0.f);
                float r1 = fmaxf(add[2 * p + 1] + hi, 0.f);
                ow[p] = cvt_pk_bf16(r0, r1);
            }
            vv = make_uint4(ow[0], ow[1], ow[2], ow[3]);
            *(uint4*)(xout + (size_t)n * HID + off) = vv;
        }
        *(uint4*)(sH + r * 136 + off) = vv;
    }
    // stage Wu
#pragma unroll
    for (int q = 0; q < 4; ++q) {
        int c = q * 512 + tid;
        int nn = c >> 4, off = (c & 15) << 3;
        *(uint4*)(sWT + nn * 136 + off) = *(const uint4*)(WuT + nn * 128 + off);
    }
    __syncthreads();

    int lane = tid & 63, wv = tid >> 6;
    int l15 = lane & 15, quad = lane >> 4;
    int ch = wv & 1, rh = wv >> 1;

    short8 afr[2][4];
#pragma unroll
    for (int rr = 0; rr < 2; ++rr) {
        const ushort* ab = sH + (rh * 32 + rr * 16 + l15) * 136 + quad * 8;
#pragma unroll
        for (int kc = 0; kc < 4; ++kc)
            afr[rr][kc] = *(const short8*)(ab + kc * 32);
    }

#pragma unroll
    for (int pass = 0; pass < 2; ++pass) {
        ushort* out = pass ? outv : outu;
        f32x4 acc[2][4];
#pragma unroll
        for (int rr = 0; rr < 2; ++rr)
#pragma unroll
            for (int ct = 0; ct < 4; ++ct) acc[rr][ct] = (f32x4){0.f, 0.f, 0.f, 0.f};
#pragma unroll
        for (int kc = 0; kc < 4; ++kc) {
#pragma unroll
            for (int ct = 0; ct < 4; ++ct) {
                short8 bfr = *(const short8*)(sWT + ((ch * 4 + ct) * 16 + l15) * 136 + quad * 8 + kc * 32);
                acc[0][ct] = __builtin_amdgcn_mfma_f32_16x16x32_bf16(afr[0][kc], bfr, acc[0][ct], 0, 0, 0);
                acc[1][ct] = __builtin_amdgcn_mfma_f32_16x16x32_bf16(afr[1][kc], bfr, acc[1][ct], 0, 0, 0);
            }
        }
        __syncthreads();   // sWT + sH(afr) reads done
#pragma unroll
        for (int ct = 0; ct < 4; ++ct) {
            int col = (ch * 4 + ct) * 16 + l15;
            float bb = pass ? bv[col] : 0.f;
#pragma unroll
            for (int rr = 0; rr < 2; ++rr) {
                int rowb = rh * 32 + rr * 16 + quad * 4;
                unsigned p01 = cvt_pk_bf16(acc[rr][ct][0] + bb, acc[rr][ct][1] + bb);
                unsigned p23 = cvt_pk_bf16(acc[rr][ct][2] + bb, acc[rr][ct][3] + bb);
                sH[(rowb + 0) * 136 + col] = (ushort)p01;
                sH[(rowb + 1) * 136 + col] = (ushort)(p01 >> 16);
                sH[(rowb + 2) * 136 + col] = (ushort)p23;
                sH[(rowb + 3) * 136 + col] = (ushort)(p23 >> 16);
            }
        }
        if (pass == 0) {   // restage Wv over sWT (reads drained by the barrier above)
#pragma unroll
            for (int q = 0; q < 4; ++q) {
                int c = q * 512 + tid;
                int nn = c >> 4, off = (c & 15) << 3;
                *(uint4*)(sWT + nn * 136 + off) = *(const uint4*)(WvT + nn * 128 + off);
            }
        }
        __syncthreads();
#pragma unroll
        for (int q = 0; q < 4; ++q) {
            int c = q * 512 + tid;
            int r = c >> 4, off = (c & 15) << 3;
            int m = n0 + r;
            if (m < N_NODES)
                *(uint4*)(out + (size_t)m * HID + off) = *(const uint4*)(sH + r * 136 + off);
        }
    }
}

// ---- edge conv: bf16 MFMA, 64-edge dst-sorted windows, 512 threads.
//      When histN != 0, every 9th block (blk%9==0) instead runs one hist2
//      block (977 of 8790): the atomic wall hides under 8x as many edge
//      compute blocks. Edge window id = (blk/9)*8 + blk%9 - 1 (exact 7813).
//      Swizzle uses the constant EDGE_G. Numerics unchanged. ----
__global__ __launch_bounds__(512, 6) void edge_kernel(const ushort* __restrict__ u,
                                                      const ushort* __restrict__ v,
                                                      const float* __restrict__ xkey,
                                                      const int* __restrict__ srcS,
                                                      const int* __restrict__ dstS,
                                                      const ushort* __restrict__ WbT,
                                                      const float* __restrict__ wlast,
                                                      unsigned* __restrict__ agg,
                                                      const int* __restrict__ dst2h,
                                                      int* __restrict__ cnt2w,
                                                      int* __restrict__ seqh,
                                                      int histN) {
    __shared__ ushort sWT[128 * 136];   // 34816 B: WbT[n][k] bf16, padded stride
    __shared__ ushort sU[64 * 136];     // 17408 B union: t[64][136] then msgT[128][66]
    __shared__ int sDst[64];
    __shared__ int sBnd[2];             // [0]=dst before window, [1]=dst after window
    __shared__ unsigned sMask[3];       // head-flag mask lo/hi + head64 flag
    int tid = threadIdx.x;

    int wg;
    if (histN) {
        int r9 = blockIdx.x % 9, q9 = blockIdx.x / 9;
        if (r9 == 0) {   // hist layer 2 role (1 in 9 blocks)
            int e = q9 * 512 + tid;
            if (e < N_EDGES) seqh[e] = atomicAdd(&cnt2w[dst2h[e]], 1);
            return;
        }
        wg = q9 * 8 + (r9 - 1);
        if (wg >= EDGE_G) return;
    } else {
        wg = blockIdx.x;
    }

    // bijective XCD chunking over the EDGE_G windows (m204 variant)
    const int nwg = EDGE_G;
    int qq = nwg >> 3, rr8 = nwg & 7;
    int xcd = wg & 7, idx = wg >> 3;
    int wgid = (xcd < rr8 ? xcd * (qq + 1) : rr8 * (qq + 1) + (xcd - rr8) * qq) + idx;
    int w0 = wgid * 64;

    // W stage: 2048 uint4 over 512 threads = 4 each (L2-hot 32KB)
#pragma unroll
    for (int q = 0; q < 4; ++q) {
        int c = q * 512 + tid;
        int n = c >> 4, off = (c & 15) << 3;
        *(uint4*)(sWT + n * 136 + off) = *(const uint4*)(WbT + n * 128 + off);
    }

    int eloc = tid >> 3;
    int sub = tid & 7;
    int kb = sub << 4;
    int lane = tid & 63, wv = tid >> 6;
    int l15 = lane & 15, quad = lane >> 4;
    int ch = wv & 1, rh = wv >> 1;

    // loop-invariant wlast slice for this thread's 16 columns -> registers
    float wreg[16];
    {
        const float4* wr4 = (const float4*)(wlast + kb);
#pragma unroll
        for (int q = 0; q < 4; ++q) {
            float4 wq = wr4[q];
            wreg[q * 4 + 0] = wq.x; wreg[q * 4 + 1] = wq.y;
            wreg[q * 4 + 2] = wq.z; wreg[q * 4 + 3] = wq.w;
        }
    }

    // phase 1: per-thread meta + gather + compute t
    {
        int e = w0 + eloc;
        if (e >= N_EDGES) e = N_EDGES - 1;   // clamp: idempotent under max
        int sx = srcS[e], sy = dstS[e];
        if (sub == 0) sDst[eloc] = sy;
        if (tid < 2) {
            int eb = (tid == 0) ? (w0 - 1) : (w0 + 64);
            sBnd[tid] = (eb >= 0 && eb < N_EDGES) ? dstS[eb] : -1;
        }
        float kd = xkey[sx] - xkey[sy];
        const uint4* ur = (const uint4*)(u + (size_t)sx * HID + kb);
        const uint4* vr = (const uint4*)(v + (size_t)sy * HID + kb);
        uint4 uu[2], vvv[2];
        uu[0] = ur[0]; uu[1] = ur[1];
        vvv[0] = vr[0]; vvv[1] = vr[1];
#pragma unroll
        for (int q = 0; q < 2; ++q) {
            unsigned pu[4] = {uu[q].x, uu[q].y, uu[q].z, uu[q].w};
            unsigned pv[4] = {vvv[q].x, vvv[q].y, vvv[q].z, vvv[q].w};
            unsigned pk[4];
#pragma unroll
            for (int p = 0; p < 4; ++p) {
                float a0 = __uint_as_float(pu[p] << 16) + __uint_as_float(pv[p] << 16);
                float a1 = __uint_as_float(pu[p] & 0xffff0000u) + __uint_as_float(pv[p] & 0xffff0000u);
                a0 = fmaf(kd, wreg[q * 8 + 2 * p], a0);
                a1 = fmaf(kd, wreg[q * 8 + 2 * p + 1], a1);
                a0 = fmaxf(a0, 0.1f * a0);   // leaky relu
                a1 = fmaxf(a1, 0.1f * a1);
                pk[p] = cvt_pk_bf16(a0, a1);
            }
            uint4 o; o.x = pk[0]; o.y = pk[1]; o.z = pk[2]; o.w = pk[3];
            *(uint4*)(sU + eloc * 136 + kb + q * 8) = o;
        }
    }
    __syncthreads();   // W-stage + t + sDst + sBnd ready

    // segment head flags: computed ONCE by wave 0 (uniform across columns)
    if (tid < 64) {
        int dprev = (tid == 0) ? sBnd[0] : sDst[tid - 1];
        unsigned long long m = __ballot(sDst[tid] != dprev);
        if (tid == 0) { sMask[0] = (unsigned)m; sMask[1] = (unsigned)(m >> 32); }
        if (tid == 63) sMask[2] = (sDst[63] != sBnd[1]) ? 1u : 0u;
    }

    // phase 2: MFMA. wave wv: rows (wv>>1)*16..+15, cols (wv&1)*64..+63
    short8 afr[4];
    {
        const ushort* ab = sU + (rh * 16 + l15) * 136 + quad * 8;
#pragma unroll
        for (int kc = 0; kc < 4; ++kc)
            afr[kc] = *(const short8*)(ab + kc * 32);
    }
    f32x4 acc[4];
#pragma unroll
    for (int ct = 0; ct < 4; ++ct) acc[ct] = (f32x4){0.f, 0.f, 0.f, 0.f};
#pragma unroll
    for (int kc = 0; kc < 4; ++kc) {
#pragma unroll
        for (int ct = 0; ct < 4; ++ct) {
            short8 bfr = *(const short8*)(sWT + ((ch * 4 + ct) * 16 + l15) * 136 + quad * 8 + kc * 32);
            acc[ct] = __builtin_amdgcn_mfma_f32_16x16x32_bf16(afr[kc], bfr, acc[ct], 0, 0, 0);
        }
    }
    __syncthreads();   // all t reads done -> sU reusable

    // epilogue: msgT[col][edge] bf16, stride 66 (odd dword stride -> conflict-free)
#pragma unroll
    for (int ct = 0; ct < 4; ++ct) {
        int col = (ch * 4 + ct) * 16 + l15;
        uint2 pr;
        pr.x = cvt_pk_bf16(acc[ct][0], acc[ct][1]);
        pr.y = cvt_pk_bf16(acc[ct][2], acc[ct][3]);
        *(uint2*)(sU + col * 66 + rh * 16 + quad * 4) = pr;
    }
    __syncthreads();

    // phase 3: mask-driven segmented max, 4 threads/col (16 edges each).
    {
        int j = tid & 127;
        int q4 = tid >> 7;            // 0..3 (wave-uniform)
        int base = q4 * 16;
        const ushort* mrow = sU + j * 66 + base;
        float vals[16];
#pragma unroll
        for (int q = 0; q < 4; ++q) {
            ushort4 mv = *(const ushort4*)(mrow + q * 4);
            vals[q * 4 + 0] = bf2f(mv.x);
            vals[q * 4 + 1] = bf2f(mv.y);
            vals[q * 4 + 2] = bf2f(mv.z);
            vals[q * 4 + 3] = bf2f(mv.w);
        }
        unsigned mlo = __builtin_amdgcn_readfirstlane(sMask[0]);
        unsigned mhi = __builtin_amdgcn_readfirstlane(sMask[1]);
        unsigned b64 = __builtin_amdgcn_readfirstlane(sMask[2]);
        unsigned long long mask = ((unsigned long long)mhi << 32) | mlo;
        unsigned slice = (unsigned)((mask >> base) & 0xFFFFull);
        unsigned nextbit = (q4 == 3) ? (b64 & 1u) : (unsigned)((mask >> (base + 16)) & 1ull);
        unsigned ext = slice | (nextbit << 16);
        bool contFrom = !(ext & 1u);
        float run = 0.f;
        bool first = true;
#pragma unroll
        for (int e3 = 0; e3 < 16; ++e3) {
            float vv2 = vals[e3];
            bool hb = (ext >> e3) & 1u;
            run = (e3 == 0 || hb) ? vv2 : fmaxf(run, vv2);
            bool end = (e3 == 15) || ((ext >> (e3 + 1)) & 1u);
            if (end) {
                int d = sDst[base + e3];
                unsigned en = encf(run);
                unsigned* ap = agg + (size_t)d * HID + j;
                bool useAtomic = (first && contFrom) || ((e3 == 15) && !nextbit);
                if (useAtomic) atomicMax(ap, en);
                else *ap = en;
                first = false;
            }
        }
    }
}

// ---- pooling with fused layer-2 combine: x2 never materialized; 16 slices/graph ----
__global__ __launch_bounds__(256) void pool_kernel(const ushort* __restrict__ x1,
                                                   const unsigned* __restrict__ agg2,
                                                   const float* __restrict__ b2b,
                                                   const int* __restrict__ cnt2,
                                                   const int* __restrict__ batch,
                                                   float* __restrict__ pooled) {
    int g = blockIdx.x >> 4, s = blockIdx.x & 15;
    int tid = threadIdx.x;
    int lo = 0, hi = N_NODES;
    while (lo < hi) { int mid = (lo + hi) >> 1; if (batch[mid] < g) lo = mid + 1; else hi = mid; }
    int start = lo;
    hi = N_NODES;
    while (lo < hi) { int mid = (lo + hi) >> 1; if (batch[mid] < g + 1) lo = mid + 1; else hi = mid; }
    int end = lo;
    int cnt = end - start;
    int b0 = start + (int)((long long)cnt * s / 16);
    int b1 = start + (int)((long long)cnt * (s + 1) / 16);
    if (b1 <= b0) return;
    int j = tid & 127;
    bool isx2 = tid >= 128;
    float bbj = isx2 ? b2b[j] : 0.f;
    float mx = -INFINITY, sm = 0.f;
    for (int n = b0; n < b1; ++n) {
        float xv = bf2f(x1[(size_t)n * HID + j]);
        float vv;
        if (isx2) {
            float a = 0.f;
            if (cnt2[n] > 0) a = decf(agg2[(size_t)n * HID + j]) + bbj;
            vv = fmaxf(a + xv, 0.f);
        } else {
            vv = xv;
        }
        mx = fmaxf(mx, vv);
        sm += vv;
    }
    atomicMax((unsigned*)pooled + (size_t)g * 512 + tid, encf(mx));
    atomicAdd(pooled + (size_t)g * 512 + 256 + tid, sm);
}

// ---- final MLP + log_softmax ----
__global__ __launch_bounds__(128) void final_kernel(const float* __restrict__ pooled,
                                                    const int* __restrict__ batch,
                                                    const float* __restrict__ Wf1,
                                                    const float* __restrict__ bf1,
                                                    const float* __restrict__ Wf2,
                                                    const float* __restrict__ bf2,
                                                    float* __restrict__ out) {
    __shared__ float sP[512];
    __shared__ float sH[128];
    int g = blockIdx.x, tid = threadIdx.x;
    int lo = 0, hi = N_NODES;
    while (lo < hi) { int mid = (lo + hi) >> 1; if (batch[mid] < g) lo = mid + 1; else hi = mid; }
    int start = lo;
    hi = N_NODES;
    while (lo < hi) { int mid = (lo + hi) >> 1; if (batch[mid] < g + 1) lo = mid + 1; else hi = mid; }
    int cnt = lo - start;
    float inv = 1.f / (float)(cnt > 1 ? cnt : 1);
#pragma unroll
    for (int q = 0; q < 4; ++q) {
        int idx = q * 128 + tid;
        float raw;
        if (idx < 256) {
            unsigned e = ((const unsigned*)pooled)[(size_t)g * 512 + idx];
            raw = (e == 0u) ? 0.f : decf(e);
        } else {
            raw = pooled[(size_t)g * 512 + idx] * inv;
        }
        sP[idx] = raw;
    }
    __syncthreads();
    float acc = bf1[tid];
    for (int k = 0; k < 512; ++k) acc = fmaf(sP[k], Wf1[k * HID + tid], acc);
    sH[tid] = fmaxf(acc, 0.f);
    __syncthreads();
    if (tid < 2) {
        float l = bf2[tid];
        for (int k = 0; k < 128; ++k) l = fmaf(sH[k], Wf2[k * 2 + tid], l);
        sP[tid] = l;
    }
    __syncthreads();
    if (tid == 0) {
        float l0 = sP[0], l1 = sP[1];
        float m = fmaxf(l0, l1);
        float ls = m + logf(expf(l0 - m) + expf(l1 - m));
        out[g * 2 + 0] = l0 - ls;
        out[g * 2 + 1] = l1 - ls;
    }
}

extern "C" void kernel_launch(void* const* d_in, const int* in_sizes, int n_in,
                              void* d_out, int out_size, void* d_ws, size_t ws_size,
                              hipStream_t stream) {
    const float* x     = (const float*)d_in[0];
    const float* W_enc = (const float*)d_in[1];
    const float* b_enc = (const float*)d_in[2];
    const float* W0    = (const float*)d_in[3];
    const float* b0    = (const float*)d_in[4];
    const float* W1a   = (const float*)d_in[5];
    const float* b1a   = (const float*)d_in[6];
    const float* W1b   = (const float*)d_in[7];
    const float* b1b   = (const float*)d_in[8];
    const float* W2a   = (const float*)d_in[9];
    const float* b2a   = (const float*)d_in[10];
    const float* W2b   = (const float*)d_in[11];
    const float* b2b   = (const float*)d_in[12];
    const float* Wf1   = (const float*)d_in[13];
    const float* bf1   = (const float*)d_in[14];
    const float* Wf2   = (const float*)d_in[15];
    const float* bf2   = (const float*)d_in[16];
    const int* src1    = (const int*)d_in[17];
    const int* dst1    = (const int*)d_in[18];
    const int* src2    = (const int*)d_in[19];
    const int* dst2    = (const int*)d_in[20];
    const int* batch   = (const int*)d_in[21];

    const size_t NB = (size_t)N_NODES * HID;     // 12.8M elements
    ushort* hbuf  = (ushort*)d_ws;               // h -> x1 (in place, bf16)
    unsigned* agg1 = (unsigned*)(hbuf + NB);     // layer-1 segment-max (u32 encoded)
    unsigned* agg2 = agg1 + NB;                  // layer-2 segment-max
    ushort* ubuf  = (ushort*)(agg2 + NB);        // u bf16
    ushort* vbuf  = ubuf + NB;                   // v bf16
    ushort* WT    = vbuf + NB;                   // 6 x 16384 bf16: Wb1,Wb2,Wu1,Wv1,Wu2,Wv2
    ushort* WbT1 = WT;
    ushort* WbT2 = WT + 1 * HID * HID;
    ushort* WuT1 = WT + 2 * HID * HID;
    ushort* WvT1 = WT + 3 * HID * HID;
    ushort* WuT2 = WT + 4 * HID * HID;
    ushort* WvT2 = WT + 5 * HID * HID;
    float* wkey  = (float*)(WT + 6 * HID * HID);
    float* bias0 = wkey + 128;
    float* xkey  = bias0 + 128;                  // dense per-node key (N_NODES fp32)
    float* pooled = xkey + N_NODES;              // 128*512 fp32
    int* cnt    = (int*)(pooled + 128 * 512);    // 2*N_NODES bucket totals (layer1 | layer2)
    int* cursor = cnt + 2 * N_NODES;             // 2*N_NODES local-exclusive (layer1 | layer2)
    int* partials1 = cursor + 2 * N_NODES;       // 512
    int* partials2 = partials1 + 512;            // 512
    int* srcS = partials2 + 512;                 // 2*N_EDGES sorted src
    int* dstS = srcS + 2 * N_EDGES;              // 2*N_EDGES sorted dst (dense expand)
    int* seq  = dstS + 2 * N_EDGES;              // 2*N_EDGES within-bucket rank

    const int prepGrid = E256_G + 385 + 256;           // hist1 + transpose+prep+zero
    const int buildMmGrid = MM_G + AH_G + BH_G;        // mm1(enc) + expand1 + scatter1
    const int mm2Grid = BH_G + AH_G + MM_G;            // scatter2 + expand2 + mm2
    const int edge1Grid = EDGE_G + BH_G;               // 8790: edge1 + embedded hist2 (1-in-9)

    hipMemsetAsync(cnt, 0, 2 * N_NODES * sizeof(int), stream);
    prep_hist_kernel<<<prepGrid, 256, 0, stream>>>(W1b, W2b, W1a, W2a, W_enc, b_enc, W0, b0,
                                                   WT, wkey, bias0, pooled, dst1, cnt, seq);
    scan_half_kernel<<<SCANH_B, 256, 0, stream>>>(cnt, cursor, partials1);
    scan2_half_kernel<<<1, 512, 0, stream>>>(partials1);

    // ---- fused: mm1 (inline encode) + expand1 + scatter1 ----
    build_mm_kernel<<<buildMmGrid, 512, 0, stream>>>(x, W0, wkey, bias0, hbuf, xkey,
                                                     WuT1, WvT1, b1a, ubuf, vbuf,
                                                     src1, dst1, cnt, cursor, partials1,
                                                     seq, srcS, dstS, agg1);

    // ---- layer 1 edge WITH embedded hist2 (1-in-9 blocks; 8:1 compute:latency) ----
    edge_kernel<<<edge1Grid, 512, 0, stream>>>(ubuf, vbuf, xkey, srcS, dstS, WbT1,
                                               W1a + 256 * HID, agg1,
                                               dst2, cnt + N_NODES, seq + N_EDGES, 1);

    // ---- layer-2 scan (inputs ready from edge1's hist role) ----
    scan_half_kernel<<<SCANH_B, 256, 0, stream>>>(cnt + N_NODES, cursor + N_NODES, partials2);
    scan2_half_kernel<<<1, 512, 0, stream>>>(partials2);

    // ---- fused: scatter2 + expand2 + mm2 (layer-1 combine; writes x1 to hbuf) ----
    mm2_build2_kernel<<<mm2Grid, 512, 0, stream>>>(hbuf, agg1, cnt, b1b, hbuf,
                                                   WuT2, WvT2, b2a, ubuf, vbuf,
                                                   src2, dst2, cnt + N_NODES, cursor + N_NODES,
                                                   partials2, seq, srcS, dstS, agg2);
    edge_kernel<<<EDGE_G, 512, 0, stream>>>(ubuf, vbuf, xkey, srcS + N_EDGES, dstS + N_EDGES,
                                            WbT2, W2a + 256 * HID, agg2,
                                            nullptr, nullptr, nullptr, 0);

    // ---- pooling (layer-2 combine fused; pooled zeroed by prep_hist) + head ----
    pool_kernel<<<N_GRAPHS * 16, 256, 0, stream>>>(hbuf, agg2, b2b, cnt + N_NODES, batch, pooled);
    final_kernel<<<N_GRAPHS, 128, 0, stream>>>(pooled, batch, Wf1, bf1, Wf2, bf2, (float*)d_out);
}